// Round 15
// baseline (143.504 us; speedup 1.0000x reference)
//
#include <hip/hip_runtime.h>
#include <hip/hip_bf16.h>
#include <math.h>

#define BB 4
#define NN 512
#define DD 64
#define HH 8
#define DKK 8

typedef float f32x4 __attribute__((ext_vector_type(4)));
typedef short s16x8 __attribute__((ext_vector_type(8)));

__device__ __forceinline__ void split8(const float* fv, s16x8& hi, s16x8& lo) {
#pragma unroll
    for (int j = 0; j < 8; ++j) {
        const unsigned u = __float_as_uint(fv[j]);
        hi[j] = (short)(u >> 16);
        const float r = fv[j] - __uint_as_float(u & 0xFFFF0000u);
        lo[j] = (short)(__float_as_uint(r) >> 16);
    }
}

__device__ __forceinline__ short bf16rne(float f) {
    return (short)((__float_as_uint(f) + 0x8000u) >> 16);
}

// packed bf16 conversion: 8 floats -> s16x8 via 4x v_cvt_pk_bf16_f32
__device__ __forceinline__ s16x8 cvt8(const float4& a, const float4& b) {
    union { __hip_bfloat162 h; unsigned u; } c0, c1, c2, c3;
    c0.h = __float22bfloat162_rn(make_float2(a.x, a.y));
    c1.h = __float22bfloat162_rn(make_float2(a.z, a.w));
    c2.h = __float22bfloat162_rn(make_float2(b.x, b.y));
    c3.h = __float22bfloat162_rn(make_float2(b.z, b.w));
    union { unsigned u[4]; s16x8 s; } r;
    r.u[0] = c0.u; r.u[1] = c1.u; r.u[2] = c2.u; r.u[3] = c3.u;
    return r.s;
}

// tile-local LDS byte offset with XOR swizzle (row = 256B)
__device__ __forceinline__ int swz(int r, int cb) {
    return r * 256 + (cb ^ ((r & 7) << 4));
}

// ---------------- Kernel 1: QKV projection ----------------
__global__ __launch_bounds__(64) void qkv_kernel(
    const float* __restrict__ n,
    const float* __restrict__ Wq,
    const float* __restrict__ Wk,
    const float* __restrict__ Wv,
    float* __restrict__ Q,
    float* __restrict__ K,
    float* __restrict__ V)
{
    const int row = blockIdx.x;
    const int j = threadIdx.x;
    __shared__ __align__(16) float nr[DD];
    nr[j] = n[(size_t)row * DD + j];
    __syncthreads();
    float q = 0.f, k = 0.f, v = 0.f;
#pragma unroll
    for (int d = 0; d < DD; ++d) {
        const float nv = nr[d];
        q = fmaf(nv, Wq[d * DD + j], q);
        k = fmaf(nv, Wk[d * DD + j], k);
        v = fmaf(nv, Wv[d * DD + j], v);
    }
    Q[(size_t)row * DD + j] = q;
    K[(size_t)row * DD + j] = k;
    V[(size_t)row * DD + j] = v;
}

// ---------------- Kernel 1b: precompute K MFMA fragments ----------------
__global__ __launch_bounds__(64) void kfrag_kernel(
    const float* __restrict__ K,
    unsigned short* __restrict__ Kf)
{
    const int blk = blockIdx.x;          // b*32 + T
    const int b = blk >> 5;
    const int T = blk & 31;
    const int lane = threadIdx.x;
    const int cc = lane & 15;
    const int kg = lane >> 4;

    const float* src = K + ((size_t)b * NN + T * 16 + cc) * DD + kg * 8;
    const float4 k0 = *(const float4*)(src);
    const float4 k1 = *(const float4*)(src + 4);
    const float4 k2 = *(const float4*)(src + 32);
    const float4 k3 = *(const float4*)(src + 36);
    const s16x8 kh0 = cvt8(k0, k1);
    const s16x8 kh1 = cvt8(k2, k3);
    s16x8* out = (s16x8*)Kf;
    out[((size_t)blk * 2 + 0) * 64 + lane] = kh0;
    out[((size_t)blk * 2 + 1) * 64 + lane] = kh1;
}

// ---------------- Kernel 2: fused edge + attention, 32 KB LDS ----------------
// Block = one row, 4 waves. LDS layout (32768 B exactly -> 5 blocks/CU):
//   [0,16384):  4 x 4KB per-wave slice, reused for BOTH e-in and out staging,
//               then (after streaming barrier) aliased for gpart/gsum/vh.
//   [16384,32768): eb[8][512] fp32 (Eb matrix for softmax).
__global__ __launch_bounds__(256) void attn_kernel(
    const float* __restrict__ e,
    const float* __restrict__ Q,
    const unsigned short* __restrict__ Kf,
    const float* __restrict__ V,
    const float* __restrict__ We,   // [64][8]
    const float* __restrict__ Wg,   // [64][8]
    const float* __restrict__ Oe,   // [8][64]
    const float* __restrict__ On,   // [64][64]
    float* __restrict__ n_out,      // [B][N][64]
    float* __restrict__ e_out)      // [B][N][N][64]
{
    const int row = blockIdx.x;
    const int b = row >> 9;
    const int t = threadIdx.x;
    const int lane = t & 63;
    const int wv = t >> 6;             // wave = quarter
    const int cc = lane & 15;
    const int kg = lane >> 4;
    const int wr = lane >> 4;          // coalesced map: sub-row
    const int wc = (lane & 15) << 4;   // coalesced map: byte col

    __shared__ __align__(16) char smem[32768];
    char* le = smem + wv * 4096;                         // per-wave e/o slice
    float (*eb)[NN] = (float(*)[NN])(smem + 16384);      // eb[8][512]
    float* gpart = (float*)smem;                         // [4][8]  (after bar)
    float* gsum  = (float*)(smem + 128);                 // [8]     (after bar)
    float* vh    = (float*)(smem + 192);                 // [64]    (after bar)

    const float scale = 0.35355339059327373f;

    // Qx fragments: Qx[h][d] = Q[d] * (d>>3 == h); nonzero iff cc==4ks+kg
    s16x8 qxh0 = {0,0,0,0,0,0,0,0}, qxh1 = {0,0,0,0,0,0,0,0};
    {
        const float* Qr = Q + (size_t)row * DD;
        if (cc == kg) {
#pragma unroll
            for (int j = 0; j < 8; ++j) qxh0[j] = bf16rne(Qr[kg * 8 + j]);
        }
        if (cc == 4 + kg) {
#pragma unroll
            for (int j = 0; j < 8; ++j) qxh1[j] = bf16rne(Qr[32 + kg * 8 + j]);
        }
    }

    // GEMM1 A operand: Wc=[We|Wg]; lane holds Wc[k=ks*32+kg*8+j][cc]
    s16x8 b1h0, b1l0, b1h1, b1l1;
    {
        float fv[8];
#pragma unroll
        for (int j = 0; j < 8; ++j) {
            const int k = kg * 8 + j;
            fv[j] = (cc < 8) ? We[k * HH + cc] : Wg[k * HH + (cc - 8)];
        }
        split8(fv, b1h0, b1l0);
#pragma unroll
        for (int j = 0; j < 8; ++j) {
            const int k = 32 + kg * 8 + j;
            fv[j] = (cc < 8) ? We[k * HH + cc] : Wg[k * HH + (cc - 8)];
        }
        split8(fv, b1h1, b1l1);
    }
    // GEMM2 A operand: lane holds Oe[k=kg*8+j][nt*16+cc], kg==0 valid
    s16x8 b2h[4], b2l[4];
#pragma unroll
    for (int nt = 0; nt < 4; ++nt) {
        float fv[8];
#pragma unroll
        for (int j = 0; j < 8; ++j)
            fv[j] = (kg == 0) ? Oe[j * DD + nt * 16 + cc] : 0.f;
        split8(fv, b2h[nt], b2l[nt]);
    }

    float gs0 = 0.f, gs1 = 0.f, gs2 = 0.f, gs3 = 0.f;
    const float* __restrict__ e_row = e + (size_t)row * NN * DD;
    const s16x8* __restrict__ kfp = (const s16x8*)Kf;
    float* __restrict__ eo = e_out + (size_t)row * NN * DD;
    const int T0 = wv * 8;
    const int lastT = T0 + 7;
    const int kbase = b * 32;

    // A = even tiles, B = odd tiles
    float4 eA0, eA1, eA2, eA3, eB0, eB1, eB2, eB3;
    s16x8 kfA0, kfA1, kfB0, kfB1;
    {
        const float* se = e_row + (size_t)T0 * 16 * DD + lane * 4;
        eA0 = *(const float4*)(se);        eA1 = *(const float4*)(se + 256);
        eA2 = *(const float4*)(se + 512);  eA3 = *(const float4*)(se + 768);
        kfA0 = kfp[((size_t)(kbase + T0) * 2 + 0) * 64 + lane];
        kfA1 = kfp[((size_t)(kbase + T0) * 2 + 1) * 64 + lane];
        const float* se2 = e_row + (size_t)(T0 + 1) * 16 * DD + lane * 4;
        eB0 = *(const float4*)(se2);       eB1 = *(const float4*)(se2 + 256);
        eB2 = *(const float4*)(se2 + 512); eB3 = *(const float4*)(se2 + 768);
        kfB0 = kfp[((size_t)(kbase + T0 + 1) * 2 + 0) * 64 + lane];
        kfB1 = kfp[((size_t)(kbase + T0 + 1) * 2 + 1) * 64 + lane];
    }

    auto body = [&](int T,
                    float4& p0, float4& p1, float4& p2, float4& p3,
                    s16x8& kh0, s16x8& kh1) {
        const int m0 = T * 16;

        // 1. stage consumed e regs -> per-wave LDS slice (swizzled bounce)
        //    (in-order LDS per wave: prior body's step-8 reads already done)
        *(float4*)(le + swz(0 + wr, wc)) = p0;
        *(float4*)(le + swz(4 + wr, wc)) = p1;
        *(float4*)(le + swz(8 + wr, wc)) = p2;
        *(float4*)(le + swz(12 + wr, wc)) = p3;

        // 2. use K frags now, then reissue loads for tile T+2
        const s16x8 kc0 = kh0, kc1 = kh1;
        {
            int Tn = T + 2; if (Tn > lastT) Tn = lastT;
            const float* se = e_row + (size_t)Tn * 16 * DD + lane * 4;
            p0 = *(const float4*)(se);        p1 = *(const float4*)(se + 256);
            p2 = *(const float4*)(se + 512);  p3 = *(const float4*)(se + 768);
            kh0 = kfp[((size_t)(kbase + Tn) * 2 + 0) * 64 + lane];
            kh1 = kfp[((size_t)(kbase + Tn) * 2 + 1) * 64 + lane];
        }

        // 3. e fragment reads from LDS
        const float4 ef0 = *(const float4*)(le + swz(cc, kg * 32));
        const float4 ef1 = *(const float4*)(le + swz(cc, kg * 32 + 16));
        const float4 ef2 = *(const float4*)(le + swz(cc, 128 + kg * 32));
        const float4 ef3 = *(const float4*)(le + swz(cc, 128 + kg * 32 + 16));

        // 4. packed bf16 conversion
        const s16x8 a1h0 = cvt8(ef0, ef1);
        const s16x8 a1h1 = cvt8(ef2, ef3);

        // 5. A-GEMM: accA[r] = A[h=kg*4+r][m0+cc] (rows 8..15 zero)
        f32x4 accA = {0.f, 0.f, 0.f, 0.f};
        accA = __builtin_amdgcn_mfma_f32_16x16x32_bf16(qxh0, kc0, accA, 0, 0, 0);
        accA = __builtin_amdgcn_mfma_f32_16x16x32_bf16(qxh1, kc1, accA, 0, 0, 0);

        // GEMM1 transposed: accEG[r] = [E|G][c=kg*4+r][m0+cc]
        f32x4 accEG = {0.f, 0.f, 0.f, 0.f};
        accEG = __builtin_amdgcn_mfma_f32_16x16x32_bf16(b1h0, a1h0, accEG, 0, 0, 0);
        accEG = __builtin_amdgcn_mfma_f32_16x16x32_bf16(b1l0, a1h0, accEG, 0, 0, 0);
        accEG = __builtin_amdgcn_mfma_f32_16x16x32_bf16(b1h1, a1h1, accEG, 0, 0, 0);
        accEG = __builtin_amdgcn_mfma_f32_16x16x32_bf16(b1l1, a1h1, accEG, 0, 0, 0);

        // 6. Eb -> eb / sigmoid partials
        float ebr0 = 0.f, ebr1 = 0.f, ebr2 = 0.f, ebr3 = 0.f;
        if (kg < 2) {
            const float a0 = fminf(fmaxf(accA[0] * scale, -5.f), 5.f);
            const float a1 = fminf(fmaxf(accA[1] * scale, -5.f), 5.f);
            const float a2 = fminf(fmaxf(accA[2] * scale, -5.f), 5.f);
            const float a3 = fminf(fmaxf(accA[3] * scale, -5.f), 5.f);
            ebr0 = a0 + accEG[0];
            ebr1 = a1 + accEG[1];
            ebr2 = a2 + accEG[2];
            ebr3 = a3 + accEG[3];
            const int h0 = kg * 4;
            const int m = m0 + cc;
            eb[h0 + 0][m] = ebr0;
            eb[h0 + 1][m] = ebr1;
            eb[h0 + 2][m] = ebr2;
            eb[h0 + 3][m] = ebr3;
        } else {
            gs0 += 1.f / (1.f + __expf(-accEG[0]));
            gs1 += 1.f / (1.f + __expf(-accEG[1]));
            gs2 += 1.f / (1.f + __expf(-accEG[2]));
            gs3 += 1.f / (1.f + __expf(-accEG[3]));
        }

        // heads 4..7 from partner lane group (kg 0<->1)
        const float pm0 = __shfl_xor(ebr0, 16, 64);
        const float pm1 = __shfl_xor(ebr1, 16, 64);
        const float pm2 = __shfl_xor(ebr2, 16, 64);
        const float pm3 = __shfl_xor(ebr3, 16, 64);

        s16x8 a2h, a2l;
        {
            float mj[8] = {ebr0, ebr1, ebr2, ebr3, pm0, pm1, pm2, pm3};
            split8(mj, a2h, a2l);
        }
        if (lane >= 16) {
            a2h = s16x8{0, 0, 0, 0, 0, 0, 0, 0};
            a2l = s16x8{0, 0, 0, 0, 0, 0, 0, 0};
        }

        // 7. GEMM2 swapped -> stage C[d][m] frags into same slice (e dead now)
#pragma unroll
        for (int nt = 0; nt < 4; ++nt) {
            f32x4 c2 = {0.f, 0.f, 0.f, 0.f};
            c2 = __builtin_amdgcn_mfma_f32_16x16x32_bf16(b2h[nt], a2h, c2, 0, 0, 0);
            c2 = __builtin_amdgcn_mfma_f32_16x16x32_bf16(b2h[nt], a2l, c2, 0, 0, 0);
            c2 = __builtin_amdgcn_mfma_f32_16x16x32_bf16(b2l[nt], a2h, c2, 0, 0, 0);
            float4 st;
            st.x = c2[0]; st.y = c2[1]; st.z = c2[2]; st.w = c2[3];
            *(float4*)(le + swz(cc, nt * 64 + kg * 16)) = st;
        }

        // 8. coalesced e_out stores (1024B contiguous per instruction)
        {
            float* eob = eo + (size_t)m0 * DD + lane * 4;
            const float4 o0 = *(const float4*)(le + swz(0 + wr, wc));
            const float4 o1 = *(const float4*)(le + swz(4 + wr, wc));
            const float4 o2 = *(const float4*)(le + swz(8 + wr, wc));
            const float4 o3 = *(const float4*)(le + swz(12 + wr, wc));
            *(float4*)(eob)       = o0;
            *(float4*)(eob + 256) = o1;
            *(float4*)(eob + 512) = o2;
            *(float4*)(eob + 768) = o3;
        }
    };

#pragma unroll 1
    for (int s4 = 0; s4 < 4; ++s4) {
        body(T0 + 2 * s4,     eA0, eA1, eA2, eA3, kfA0, kfA1);
        body(T0 + 2 * s4 + 1, eB0, eB1, eB2, eB3, kfB0, kfB1);
    }

    // sigmoid partial reduce (kg=2: heads 0-3, kg=3: heads 4-7)
    gs0 += __shfl_xor(gs0, 1, 64); gs0 += __shfl_xor(gs0, 2, 64);
    gs0 += __shfl_xor(gs0, 4, 64); gs0 += __shfl_xor(gs0, 8, 64);
    gs1 += __shfl_xor(gs1, 1, 64); gs1 += __shfl_xor(gs1, 2, 64);
    gs1 += __shfl_xor(gs1, 4, 64); gs1 += __shfl_xor(gs1, 8, 64);
    gs2 += __shfl_xor(gs2, 1, 64); gs2 += __shfl_xor(gs2, 2, 64);
    gs2 += __shfl_xor(gs2, 4, 64); gs2 += __shfl_xor(gs2, 8, 64);
    gs3 += __shfl_xor(gs3, 1, 64); gs3 += __shfl_xor(gs3, 2, 64);
    gs3 += __shfl_xor(gs3, 4, 64); gs3 += __shfl_xor(gs3, 8, 64);

    __syncthreads();   // ALL streaming done -> wave slices are dead; eb ready

    if (lane == 32) {
        gpart[wv * 8 + 0] = gs0; gpart[wv * 8 + 1] = gs1;
        gpart[wv * 8 + 2] = gs2; gpart[wv * 8 + 3] = gs3;
    }
    if (lane == 48) {
        gpart[wv * 8 + 4] = gs0; gpart[wv * 8 + 5] = gs1;
        gpart[wv * 8 + 6] = gs2; gpart[wv * 8 + 7] = gs3;
    }
    __syncthreads();
    if (t < HH) gsum[t] = gpart[t] + gpart[8 + t] + gpart[16 + t] + gpart[24 + t];
    __syncthreads();

    // ---- softmax + PV: wave wv handles h = wv and wv+4 (verified tail) ----
    const float* __restrict__ Vb = V + (size_t)b * NN * DD;
#pragma unroll
    for (int hh = 0; hh < 2; ++hh) {
        const int h = wv + hh * 4;
        float x[8];
#pragma unroll
        for (int k = 0; k < 8; ++k) x[k] = eb[h][lane + (k << 6)];
        float mx = x[0];
#pragma unroll
        for (int k = 1; k < 8; ++k) mx = fmaxf(mx, x[k]);
        mx = fmaxf(mx, __shfl_xor(mx, 1, 64));
        mx = fmaxf(mx, __shfl_xor(mx, 2, 64));
        mx = fmaxf(mx, __shfl_xor(mx, 4, 64));
        mx = fmaxf(mx, __shfl_xor(mx, 8, 64));
        mx = fmaxf(mx, __shfl_xor(mx, 16, 64));
        mx = fmaxf(mx, __shfl_xor(mx, 32, 64));
        float p[8];
        float s = 0.f;
#pragma unroll
        for (int k = 0; k < 8; ++k) { p[k] = __expf(x[k] - mx); s += p[k]; }
        s += __shfl_xor(s, 1, 64);
        s += __shfl_xor(s, 2, 64);
        s += __shfl_xor(s, 4, 64);
        s += __shfl_xor(s, 8, 64);
        s += __shfl_xor(s, 16, 64);
        s += __shfl_xor(s, 32, 64);

        float pv[8];
#pragma unroll
        for (int dk = 0; dk < 8; ++dk) pv[dk] = 0.f;
#pragma unroll
        for (int k = 0; k < 8; ++k) {
            const float* vr = Vb + (size_t)(lane + (k << 6)) * DD + h * DKK;
            const float4 va = *(const float4*)vr;
            const float4 vb2 = *(const float4*)(vr + 4);
            const float pk = p[k];
            pv[0] = fmaf(pk, va.x, pv[0]);
            pv[1] = fmaf(pk, va.y, pv[1]);
            pv[2] = fmaf(pk, va.z, pv[2]);
            pv[3] = fmaf(pk, va.w, pv[3]);
            pv[4] = fmaf(pk, vb2.x, pv[4]);
            pv[5] = fmaf(pk, vb2.y, pv[5]);
            pv[6] = fmaf(pk, vb2.z, pv[6]);
            pv[7] = fmaf(pk, vb2.w, pv[7]);
        }
#pragma unroll
        for (int dk = 0; dk < 8; ++dk) {
            float x2 = pv[dk];
            x2 += __shfl_xor(x2, 1, 64);
            x2 += __shfl_xor(x2, 2, 64);
            x2 += __shfl_xor(x2, 4, 64);
            x2 += __shfl_xor(x2, 8, 64);
            x2 += __shfl_xor(x2, 16, 64);
            x2 += __shfl_xor(x2, 32, 64);
            pv[dk] = x2;
        }
        if (lane == 0) {
            const float sc = log1pf(gsum[h]) / s;
#pragma unroll
            for (int dk = 0; dk < 8; ++dk) vh[h * DKK + dk] = pv[dk] * sc;
        }
    }
    __syncthreads();

    // ---- n_out[b,i,:] = vh @ On ----
    if (t < DD) {
        const int j = t;
        float acc = 0.f;
#pragma unroll
        for (int d = 0; d < DD; ++d) acc = fmaf(vh[d], On[d * DD + j], acc);
        n_out[(size_t)row * DD + j] = acc;
    }
}

extern "C" void kernel_launch(void* const* d_in, const int* in_sizes, int n_in,
                              void* d_out, int out_size, void* d_ws, size_t ws_size,
                              hipStream_t stream) {
    const float* n  = (const float*)d_in[0];
    const float* e  = (const float*)d_in[1];
    const float* Wq = (const float*)d_in[2];
    const float* Wk = (const float*)d_in[3];
    const float* Wv = (const float*)d_in[4];
    const float* On = (const float*)d_in[5];
    const float* We = (const float*)d_in[6];
    const float* Wg = (const float*)d_in[7];
    const float* Oe = (const float*)d_in[8];

    float* out = (float*)d_out;
    float* n_out = out;
    float* e_out = out + (size_t)BB * NN * DD;

    float* Q = (float*)d_ws;
    float* K = Q + (size_t)BB * NN * DD;
    float* V = K + (size_t)BB * NN * DD;
    unsigned short* Kf = (unsigned short*)(V + (size_t)BB * NN * DD);
    // Kf: BB*32 tiles * 2 planes * 64 lanes * 8 shorts = 131072 shorts = 256 KB

    qkv_kernel<<<BB * NN, 64, 0, stream>>>(n, Wq, Wk, Wv, Q, K, V);
    kfrag_kernel<<<BB * 32, 64, 0, stream>>>(K, Kf);
    attn_kernel<<<BB * NN, 256, 0, stream>>>(e, Q, Kf, V, We, Wg, Oe, On,
                                             n_out, e_out);
}

// Round 17
// 130.798 us; speedup vs baseline: 1.0971x; 1.0971x over previous
//
#include <hip/hip_runtime.h>
#include <hip/hip_bf16.h>
#include <math.h>

#define BB 4
#define NN 512
#define NP 516
#define DD 64
#define HH 8
#define DKK 8

typedef float f32x4 __attribute__((ext_vector_type(4)));
typedef short s16x8 __attribute__((ext_vector_type(8)));

__device__ __forceinline__ void split8(const float* fv, s16x8& hi, s16x8& lo) {
#pragma unroll
    for (int j = 0; j < 8; ++j) {
        const unsigned u = __float_as_uint(fv[j]);
        hi[j] = (short)(u >> 16);
        const float r = fv[j] - __uint_as_float(u & 0xFFFF0000u);
        lo[j] = (short)(__float_as_uint(r) >> 16);
    }
}

__device__ __forceinline__ short bf16rne(float f) {
    return (short)((__float_as_uint(f) + 0x8000u) >> 16);
}

// packed bf16 conversion: 8 floats -> s16x8 via 4x v_cvt_pk_bf16_f32
__device__ __forceinline__ s16x8 cvt8(const float4& a, const float4& b) {
    union { __hip_bfloat162 h; unsigned u; } c0, c1, c2, c3;
    c0.h = __float22bfloat162_rn(make_float2(a.x, a.y));
    c1.h = __float22bfloat162_rn(make_float2(a.z, a.w));
    c2.h = __float22bfloat162_rn(make_float2(b.x, b.y));
    c3.h = __float22bfloat162_rn(make_float2(b.z, b.w));
    union { unsigned u[4]; s16x8 s; } r;
    r.u[0] = c0.u; r.u[1] = c1.u; r.u[2] = c2.u; r.u[3] = c3.u;
    return r.s;
}

// non-temporal 16B store through ext-vector type (builtin requires it)
__device__ __forceinline__ void nt_store16(float* p, const float4& v) {
    f32x4 x;
    x[0] = v.x; x[1] = v.y; x[2] = v.z; x[3] = v.w;
    __builtin_nontemporal_store(x, (f32x4*)p);
}

// tile-local LDS byte offset with XOR swizzle (row = 256B)
__device__ __forceinline__ int swz(int r, int cb) {
    return r * 256 + (cb ^ ((r & 7) << 4));
}

// ---------------- Kernel 1: QKV projection ----------------
__global__ __launch_bounds__(64) void qkv_kernel(
    const float* __restrict__ n,
    const float* __restrict__ Wq,
    const float* __restrict__ Wk,
    const float* __restrict__ Wv,
    float* __restrict__ Q,
    float* __restrict__ K,
    float* __restrict__ V)
{
    const int row = blockIdx.x;
    const int j = threadIdx.x;
    __shared__ __align__(16) float nr[DD];
    nr[j] = n[(size_t)row * DD + j];
    __syncthreads();
    float q = 0.f, k = 0.f, v = 0.f;
#pragma unroll
    for (int d = 0; d < DD; ++d) {
        const float nv = nr[d];
        q = fmaf(nv, Wq[d * DD + j], q);
        k = fmaf(nv, Wk[d * DD + j], k);
        v = fmaf(nv, Wv[d * DD + j], v);
    }
    Q[(size_t)row * DD + j] = q;
    K[(size_t)row * DD + j] = k;
    V[(size_t)row * DD + j] = v;
}

// ---------------- Kernel 1b: precompute K MFMA fragments ----------------
__global__ __launch_bounds__(64) void kfrag_kernel(
    const float* __restrict__ K,
    unsigned short* __restrict__ Kf)
{
    const int blk = blockIdx.x;          // b*32 + T
    const int b = blk >> 5;
    const int T = blk & 31;
    const int lane = threadIdx.x;
    const int cc = lane & 15;
    const int kg = lane >> 4;

    const float* src = K + ((size_t)b * NN + T * 16 + cc) * DD + kg * 8;
    const float4 k0 = *(const float4*)(src);
    const float4 k1 = *(const float4*)(src + 4);
    const float4 k2 = *(const float4*)(src + 32);
    const float4 k3 = *(const float4*)(src + 36);
    const s16x8 kh0 = cvt8(k0, k1);
    const s16x8 kh1 = cvt8(k2, k3);
    s16x8* out = (s16x8*)Kf;
    out[((size_t)blk * 2 + 0) * 64 + lane] = kh0;
    out[((size_t)blk * 2 + 1) * 64 + lane] = kh1;
}

// ---------------- Kernel 2: fused coalesced edge + attention ----------------
// Block = one row, 4 waves (R14-proven layout). e_out stores are NON-TEMPORAL
// (write-once data; bypass L2 allocation to stop evicting the e read stream).
__global__ __launch_bounds__(256) void attn_kernel(
    const float* __restrict__ e,
    const float* __restrict__ Q,
    const unsigned short* __restrict__ Kf,
    const float* __restrict__ V,
    const float* __restrict__ We,   // [64][8]
    const float* __restrict__ Wg,   // [64][8]
    const float* __restrict__ Oe,   // [8][64]
    const float* __restrict__ On,   // [64][64]
    float* __restrict__ n_out,      // [B][N][64]
    float* __restrict__ e_out)      // [B][N][N][64]
{
    const int row = blockIdx.x;
    const int b = row >> 9;
    const int t = threadIdx.x;
    const int lane = t & 63;
    const int wv = t >> 6;             // wave = quarter
    const int cc = lane & 15;
    const int kg = lane >> 4;
    const int wr = lane >> 4;          // coalesced map: sub-row
    const int wc = (lane & 15) << 4;   // coalesced map: byte col

    __shared__ __align__(16) char lds_e[4][4096];
    __shared__ __align__(16) char lds_o[4][4096];
    __shared__ __align__(16) float eb_lds[HH][NP];
    __shared__ float gpart[4][HH];
    __shared__ float gsum[HH];
    __shared__ float vh_lds[DD];

    char* le = lds_e[wv];
    char* lo = lds_o[wv];

    const float scale = 0.35355339059327373f;

    // Qx fragments: Qx[h][d] = Q[d] * (d>>3 == h); nonzero iff cc==4ks+kg
    s16x8 qxh0 = {0,0,0,0,0,0,0,0}, qxh1 = {0,0,0,0,0,0,0,0};
    {
        const float* Qr = Q + (size_t)row * DD;
        if (cc == kg) {
#pragma unroll
            for (int j = 0; j < 8; ++j) qxh0[j] = bf16rne(Qr[kg * 8 + j]);
        }
        if (cc == 4 + kg) {
#pragma unroll
            for (int j = 0; j < 8; ++j) qxh1[j] = bf16rne(Qr[32 + kg * 8 + j]);
        }
    }

    // GEMM1 A operand: Wc=[We|Wg]; lane holds Wc[k=ks*32+kg*8+j][cc]
    s16x8 b1h0, b1l0, b1h1, b1l1;
    {
        float fv[8];
#pragma unroll
        for (int j = 0; j < 8; ++j) {
            const int k = kg * 8 + j;
            fv[j] = (cc < 8) ? We[k * HH + cc] : Wg[k * HH + (cc - 8)];
        }
        split8(fv, b1h0, b1l0);
#pragma unroll
        for (int j = 0; j < 8; ++j) {
            const int k = 32 + kg * 8 + j;
            fv[j] = (cc < 8) ? We[k * HH + cc] : Wg[k * HH + (cc - 8)];
        }
        split8(fv, b1h1, b1l1);
    }
    // GEMM2 A operand: lane holds Oe[k=kg*8+j][nt*16+cc], kg==0 valid
    s16x8 b2h[4], b2l[4];
#pragma unroll
    for (int nt = 0; nt < 4; ++nt) {
        float fv[8];
#pragma unroll
        for (int j = 0; j < 8; ++j)
            fv[j] = (kg == 0) ? Oe[j * DD + nt * 16 + cc] : 0.f;
        split8(fv, b2h[nt], b2l[nt]);
    }

    float gs0 = 0.f, gs1 = 0.f, gs2 = 0.f, gs3 = 0.f;
    const float* __restrict__ e_row = e + (size_t)row * NN * DD;
    const s16x8* __restrict__ kfp = (const s16x8*)Kf;
    float* __restrict__ eo = e_out + (size_t)row * NN * DD;
    const int T0 = wv * 8;
    const int lastT = T0 + 7;
    const int kbase = b * 32;

    // A = even tiles, B = odd tiles
    float4 eA0, eA1, eA2, eA3, eB0, eB1, eB2, eB3;
    s16x8 kfA0, kfA1, kfB0, kfB1;
    {
        const float* se = e_row + (size_t)T0 * 16 * DD + lane * 4;
        eA0 = *(const float4*)(se);        eA1 = *(const float4*)(se + 256);
        eA2 = *(const float4*)(se + 512);  eA3 = *(const float4*)(se + 768);
        kfA0 = kfp[((size_t)(kbase + T0) * 2 + 0) * 64 + lane];
        kfA1 = kfp[((size_t)(kbase + T0) * 2 + 1) * 64 + lane];
        const float* se2 = e_row + (size_t)(T0 + 1) * 16 * DD + lane * 4;
        eB0 = *(const float4*)(se2);       eB1 = *(const float4*)(se2 + 256);
        eB2 = *(const float4*)(se2 + 512); eB3 = *(const float4*)(se2 + 768);
        kfB0 = kfp[((size_t)(kbase + T0 + 1) * 2 + 0) * 64 + lane];
        kfB1 = kfp[((size_t)(kbase + T0 + 1) * 2 + 1) * 64 + lane];
    }

    auto body = [&](int T,
                    float4& p0, float4& p1, float4& p2, float4& p3,
                    s16x8& kh0, s16x8& kh1) {
        const int m0 = T * 16;

        // 1. stage consumed e regs -> per-wave LDS (swizzled transpose bounce)
        *(float4*)(le + swz(0 + wr, wc)) = p0;
        *(float4*)(le + swz(4 + wr, wc)) = p1;
        *(float4*)(le + swz(8 + wr, wc)) = p2;
        *(float4*)(le + swz(12 + wr, wc)) = p3;

        // 2. use K frags now, then reissue loads for tile T+2
        const s16x8 kc0 = kh0, kc1 = kh1;
        {
            int Tn = T + 2; if (Tn > lastT) Tn = lastT;
            const float* se = e_row + (size_t)Tn * 16 * DD + lane * 4;
            p0 = *(const float4*)(se);        p1 = *(const float4*)(se + 256);
            p2 = *(const float4*)(se + 512);  p3 = *(const float4*)(se + 768);
            kh0 = kfp[((size_t)(kbase + Tn) * 2 + 0) * 64 + lane];
            kh1 = kfp[((size_t)(kbase + Tn) * 2 + 1) * 64 + lane];
        }

        // 3. e fragment reads from LDS
        const float4 ef0 = *(const float4*)(le + swz(cc, kg * 32));
        const float4 ef1 = *(const float4*)(le + swz(cc, kg * 32 + 16));
        const float4 ef2 = *(const float4*)(le + swz(cc, 128 + kg * 32));
        const float4 ef3 = *(const float4*)(le + swz(cc, 128 + kg * 32 + 16));

        // 4. packed bf16 conversion
        const s16x8 a1h0 = cvt8(ef0, ef1);
        const s16x8 a1h1 = cvt8(ef2, ef3);

        // 5. A-GEMM: accA[r] = A[h=kg*4+r][m0+cc] (rows 8..15 zero)
        f32x4 accA = {0.f, 0.f, 0.f, 0.f};
        accA = __builtin_amdgcn_mfma_f32_16x16x32_bf16(qxh0, kc0, accA, 0, 0, 0);
        accA = __builtin_amdgcn_mfma_f32_16x16x32_bf16(qxh1, kc1, accA, 0, 0, 0);

        // GEMM1 transposed: accEG[r] = [E|G][c=kg*4+r][m0+cc]
        f32x4 accEG = {0.f, 0.f, 0.f, 0.f};
        accEG = __builtin_amdgcn_mfma_f32_16x16x32_bf16(b1h0, a1h0, accEG, 0, 0, 0);
        accEG = __builtin_amdgcn_mfma_f32_16x16x32_bf16(b1l0, a1h0, accEG, 0, 0, 0);
        accEG = __builtin_amdgcn_mfma_f32_16x16x32_bf16(b1h1, a1h1, accEG, 0, 0, 0);
        accEG = __builtin_amdgcn_mfma_f32_16x16x32_bf16(b1l1, a1h1, accEG, 0, 0, 0);

        // 6. Eb -> eb_lds / sigmoid partials
        float ebr0 = 0.f, ebr1 = 0.f, ebr2 = 0.f, ebr3 = 0.f;
        if (kg < 2) {
            const float a0 = fminf(fmaxf(accA[0] * scale, -5.f), 5.f);
            const float a1 = fminf(fmaxf(accA[1] * scale, -5.f), 5.f);
            const float a2 = fminf(fmaxf(accA[2] * scale, -5.f), 5.f);
            const float a3 = fminf(fmaxf(accA[3] * scale, -5.f), 5.f);
            ebr0 = a0 + accEG[0];
            ebr1 = a1 + accEG[1];
            ebr2 = a2 + accEG[2];
            ebr3 = a3 + accEG[3];
            const int h0 = kg * 4;
            const int m = m0 + cc;
            eb_lds[h0 + 0][m] = ebr0;
            eb_lds[h0 + 1][m] = ebr1;
            eb_lds[h0 + 2][m] = ebr2;
            eb_lds[h0 + 3][m] = ebr3;
        } else {
            gs0 += 1.f / (1.f + __expf(-accEG[0]));
            gs1 += 1.f / (1.f + __expf(-accEG[1]));
            gs2 += 1.f / (1.f + __expf(-accEG[2]));
            gs3 += 1.f / (1.f + __expf(-accEG[3]));
        }

        // heads 4..7 from partner lane group (kg 0<->1)
        const float pm0 = __shfl_xor(ebr0, 16, 64);
        const float pm1 = __shfl_xor(ebr1, 16, 64);
        const float pm2 = __shfl_xor(ebr2, 16, 64);
        const float pm3 = __shfl_xor(ebr3, 16, 64);

        s16x8 a2h, a2l;
        {
            float mj[8] = {ebr0, ebr1, ebr2, ebr3, pm0, pm1, pm2, pm3};
            split8(mj, a2h, a2l);
        }
        if (lane >= 16) {
            a2h = s16x8{0, 0, 0, 0, 0, 0, 0, 0};
            a2l = s16x8{0, 0, 0, 0, 0, 0, 0, 0};
        }

        // 7. GEMM2 swapped -> stage C[d][m] frags into LDS (swizzled)
#pragma unroll
        for (int nt = 0; nt < 4; ++nt) {
            f32x4 c2 = {0.f, 0.f, 0.f, 0.f};
            c2 = __builtin_amdgcn_mfma_f32_16x16x32_bf16(b2h[nt], a2h, c2, 0, 0, 0);
            c2 = __builtin_amdgcn_mfma_f32_16x16x32_bf16(b2h[nt], a2l, c2, 0, 0, 0);
            c2 = __builtin_amdgcn_mfma_f32_16x16x32_bf16(b2l[nt], a2h, c2, 0, 0, 0);
            float4 st;
            st.x = c2[0]; st.y = c2[1]; st.z = c2[2]; st.w = c2[3];
            *(float4*)(lo + swz(cc, nt * 64 + kg * 16)) = st;
        }

        // 8. coalesced NON-TEMPORAL e_out stores (write-once, bypass L2)
        {
            float* eob = eo + (size_t)m0 * DD + lane * 4;
            const float4 o0 = *(const float4*)(lo + swz(0 + wr, wc));
            const float4 o1 = *(const float4*)(lo + swz(4 + wr, wc));
            const float4 o2 = *(const float4*)(lo + swz(8 + wr, wc));
            const float4 o3 = *(const float4*)(lo + swz(12 + wr, wc));
            nt_store16(eob,       o0);
            nt_store16(eob + 256, o1);
            nt_store16(eob + 512, o2);
            nt_store16(eob + 768, o3);
        }
    };

#pragma unroll 1
    for (int s4 = 0; s4 < 4; ++s4) {
        body(T0 + 2 * s4,     eA0, eA1, eA2, eA3, kfA0, kfA1);
        body(T0 + 2 * s4 + 1, eB0, eB1, eB2, eB3, kfB0, kfB1);
    }

    // sigmoid partial reduce (kg=2: heads 0-3, kg=3: heads 4-7)
    gs0 += __shfl_xor(gs0, 1, 64); gs0 += __shfl_xor(gs0, 2, 64);
    gs0 += __shfl_xor(gs0, 4, 64); gs0 += __shfl_xor(gs0, 8, 64);
    gs1 += __shfl_xor(gs1, 1, 64); gs1 += __shfl_xor(gs1, 2, 64);
    gs1 += __shfl_xor(gs1, 4, 64); gs1 += __shfl_xor(gs1, 8, 64);
    gs2 += __shfl_xor(gs2, 1, 64); gs2 += __shfl_xor(gs2, 2, 64);
    gs2 += __shfl_xor(gs2, 4, 64); gs2 += __shfl_xor(gs2, 8, 64);
    gs3 += __shfl_xor(gs3, 1, 64); gs3 += __shfl_xor(gs3, 2, 64);
    gs3 += __shfl_xor(gs3, 4, 64); gs3 += __shfl_xor(gs3, 8, 64);
    if (lane == 32) {
        gpart[wv][0] = gs0; gpart[wv][1] = gs1;
        gpart[wv][2] = gs2; gpart[wv][3] = gs3;
    }
    if (lane == 48) {
        gpart[wv][4] = gs0; gpart[wv][5] = gs1;
        gpart[wv][6] = gs2; gpart[wv][7] = gs3;
    }
    __syncthreads();   // eb_lds complete + gpart ready
    if (t < HH) gsum[t] = gpart[0][t] + gpart[1][t] + gpart[2][t] + gpart[3][t];
    __syncthreads();

    // ---- softmax + PV: wave wv handles h = wv and wv+4 (verified tail) ----
    const float* __restrict__ Vb = V + (size_t)b * NN * DD;
#pragma unroll
    for (int hh = 0; hh < 2; ++hh) {
        const int h = wv + hh * 4;
        float x[8];
#pragma unroll
        for (int k = 0; k < 8; ++k) x[k] = eb_lds[h][lane + (k << 6)];
        float mx = x[0];
#pragma unroll
        for (int k = 1; k < 8; ++k) mx = fmaxf(mx, x[k]);
        mx = fmaxf(mx, __shfl_xor(mx, 1, 64));
        mx = fmaxf(mx, __shfl_xor(mx, 2, 64));
        mx = fmaxf(mx, __shfl_xor(mx, 4, 64));
        mx = fmaxf(mx, __shfl_xor(mx, 8, 64));
        mx = fmaxf(mx, __shfl_xor(mx, 16, 64));
        mx = fmaxf(mx, __shfl_xor(mx, 32, 64));
        float p[8];
        float s = 0.f;
#pragma unroll
        for (int k = 0; k < 8; ++k) { p[k] = __expf(x[k] - mx); s += p[k]; }
        s += __shfl_xor(s, 1, 64);
        s += __shfl_xor(s, 2, 64);
        s += __shfl_xor(s, 4, 64);
        s += __shfl_xor(s, 8, 64);
        s += __shfl_xor(s, 16, 64);
        s += __shfl_xor(s, 32, 64);

        float pv[8];
#pragma unroll
        for (int dk = 0; dk < 8; ++dk) pv[dk] = 0.f;
#pragma unroll
        for (int k = 0; k < 8; ++k) {
            const float* vr = Vb + (size_t)(lane + (k << 6)) * DD + h * DKK;
            const float4 va = *(const float4*)vr;
            const float4 vb2 = *(const float4*)(vr + 4);
            const float pk = p[k];
            pv[0] = fmaf(pk, va.x, pv[0]);
            pv[1] = fmaf(pk, va.y, pv[1]);
            pv[2] = fmaf(pk, va.z, pv[2]);
            pv[3] = fmaf(pk, va.w, pv[3]);
            pv[4] = fmaf(pk, vb2.x, pv[4]);
            pv[5] = fmaf(pk, vb2.y, pv[5]);
            pv[6] = fmaf(pk, vb2.z, pv[6]);
            pv[7] = fmaf(pk, vb2.w, pv[7]);
        }
#pragma unroll
        for (int dk = 0; dk < 8; ++dk) {
            float x2 = pv[dk];
            x2 += __shfl_xor(x2, 1, 64);
            x2 += __shfl_xor(x2, 2, 64);
            x2 += __shfl_xor(x2, 4, 64);
            x2 += __shfl_xor(x2, 8, 64);
            x2 += __shfl_xor(x2, 16, 64);
            x2 += __shfl_xor(x2, 32, 64);
            pv[dk] = x2;
        }
        if (lane == 0) {
            const float sc = log1pf(gsum[h]) / s;
#pragma unroll
            for (int dk = 0; dk < 8; ++dk) vh_lds[h * DKK + dk] = pv[dk] * sc;
        }
    }
    __syncthreads();

    // ---- n_out[b,i,:] = vh @ On ----
    if (t < DD) {
        const int j = t;
        float acc = 0.f;
#pragma unroll
        for (int d = 0; d < DD; ++d) acc = fmaf(vh_lds[d], On[d * DD + j], acc);
        n_out[(size_t)row * DD + j] = acc;
    }
}

extern "C" void kernel_launch(void* const* d_in, const int* in_sizes, int n_in,
                              void* d_out, int out_size, void* d_ws, size_t ws_size,
                              hipStream_t stream) {
    const float* n  = (const float*)d_in[0];
    const float* e  = (const float*)d_in[1];
    const float* Wq = (const float*)d_in[2];
    const float* Wk = (const float*)d_in[3];
    const float* Wv = (const float*)d_in[4];
    const float* On = (const float*)d_in[5];
    const float* We = (const float*)d_in[6];
    const float* Wg = (const float*)d_in[7];
    const float* Oe = (const float*)d_in[8];

    float* out = (float*)d_out;
    float* n_out = out;
    float* e_out = out + (size_t)BB * NN * DD;

    float* Q = (float*)d_ws;
    float* K = Q + (size_t)BB * NN * DD;
    float* V = K + (size_t)BB * NN * DD;
    unsigned short* Kf = (unsigned short*)(V + (size_t)BB * NN * DD);
    // Kf: BB*32 tiles * 2 planes * 64 lanes * 8 shorts = 131072 shorts = 256 KB

    qkv_kernel<<<BB * NN, 64, 0, stream>>>(n, Wq, Wk, Wv, Q, K, V);
    kfrag_kernel<<<BB * 32, 64, 0, stream>>>(K, Kf);
    attn_kernel<<<BB * NN, 256, 0, stream>>>(e, Q, Kf, V, We, Wg, Oe, On,
                                             n_out, e_out);
}